// Round 4
// baseline (114.094 us; speedup 1.0000x reference)
//
#include <hip/hip_runtime.h>

// MLP: 64 × (Linear(5,5)+ReLU) then Linear(5,1), BATCH = 1048576 rows.
// fp32 VALU compute-bound. R4: v_pk_fma_f32 with SGPR-PAIR weight operands.
//
// R3 post-mortem showed ~60 extra v_mov/layer: compiler must splat each
// wave-uniform 32-bit weight into a 64-bit VGPR pair for VOP3P. Fix: a prep
// kernel duplicates every weight/bias into (w,w) pairs in d_ws. A uniform
// load of 8 bytes -> s_load_dwordx2 -> SGPR pair, which v_pk_fma_f32 takes
// DIRECTLY as its single allowed scalar operand. Zero weight-mov cost.
// 2 rows/thread (one float2 pair): 2048 blocks -> 8 waves/SIMD to hide
// scalar-cache latency (R3 had only 4 and 35% issue stall).

#define MLP_DEPTH 64
#define MLP_D 5

typedef float f2 __attribute__((ext_vector_type(2)));

// d_ws layout (all values duplicated as pairs):
//   per layer l (30 pairs, 240 B): W[j*5+i] pairs (j-major, 25), then b[j] pairs (5)
//   after 64 layers: W_out pairs (5), b_out pair (1)
__global__ __launch_bounds__(256) void MLP_prep_kernel(
    const float* __restrict__ Ws, const float* __restrict__ bs,
    const float* __restrict__ W_out, const float* __restrict__ b_out,
    float* __restrict__ ws)
{
    const int idx = blockIdx.x * blockDim.x + threadIdx.x;
    const int npairs_layers = MLP_DEPTH * 30;
    if (idx < npairs_layers) {
        const int l = idx / 30, k = idx % 30;
        const float v = (k < 25) ? Ws[l * 25 + k] : bs[l * MLP_D + (k - 25)];
        ws[2 * idx + 0] = v;
        ws[2 * idx + 1] = v;
    } else if (idx < npairs_layers + 6) {
        const int k = idx - npairs_layers;
        const float v = (k < MLP_D) ? W_out[k] : b_out[0];
        ws[2 * idx + 0] = v;
        ws[2 * idx + 1] = v;
    }
}

__global__ __launch_bounds__(256) void MLP_89687507075104_kernel(
    const float* __restrict__ x,     // [n, 5]
    const f2* __restrict__ wdup,     // duplicated pairs, layout above
    float* __restrict__ out,         // [n]
    int n)
{
    const int t = blockIdx.x * blockDim.x + threadIdx.x;
    const long row0 = (long)t * 2;
    if (row0 >= n) return;

    // 10 contiguous floats = rows row0, row0+1 (8B aligned: 40B/thread).
    float f[2 * MLP_D];
    const f2* xp = reinterpret_cast<const f2*>(x + row0 * MLP_D);
#pragma unroll
    for (int q = 0; q < 5; ++q) {
        const f2 v = xp[q];
        f[2 * q + 0] = v.x;
        f[2 * q + 1] = v.y;
    }
    // h[i] = (h_i of row0, h_i of row1)
    f2 h[MLP_D];
#pragma unroll
    for (int i = 0; i < MLP_D; ++i)
        h[i] = (f2){ f[i], f[MLP_D + i] };

#pragma unroll
    for (int l = 0; l < MLP_DEPTH; ++l) {
        const f2* wp = wdup + l * 30;   // wave-uniform, const offsets
        f2 a[MLP_D];
#pragma unroll
        for (int j = 0; j < MLP_D; ++j)
            a[j] = wp[25 + j];          // bias pair (b,b)
#pragma unroll
        for (int i = 0; i < MLP_D; ++i) {
            const f2 hi = h[i];
#pragma unroll
            for (int j = 0; j < MLP_D; ++j)
                a[j] += hi * wp[j * MLP_D + i];   // v_pk_fma_f32, scalar-pair W
        }
#pragma unroll
        for (int j = 0; j < MLP_D; ++j)
            h[j] = __builtin_elementwise_max(a[j], (f2)0.0f);  // v_pk_max_f32
    }

    // Output layer: Linear(5,1) for both rows at once.
    const f2* wo = wdup + MLP_DEPTH * 30;
    f2 o = wo[5];                        // (b_out, b_out)
#pragma unroll
    for (int i = 0; i < MLP_D; ++i)
        o += h[i] * wo[i];
    *reinterpret_cast<f2*>(out + row0) = o;
}

extern "C" void kernel_launch(void* const* d_in, const int* in_sizes, int n_in,
                              void* d_out, int out_size, void* d_ws, size_t ws_size,
                              hipStream_t stream) {
    const float* x     = (const float*)d_in[0];
    const float* Ws    = (const float*)d_in[1];
    const float* bs    = (const float*)d_in[2];
    const float* W_out = (const float*)d_in[3];
    const float* b_out = (const float*)d_in[4];
    float* out = (float*)d_out;
    float* ws  = (float*)d_ws;   // needs (64*30+6)*2*4 = 15,408 B

    const int n = in_sizes[0] / MLP_D;  // batch rows (1048576)

    // Prep: duplicate weights/biases into (w,w) pairs. Re-run every launch
    // (harness re-poisons d_ws before each timed call).
    const int npairs = MLP_DEPTH * 30 + 6;
    MLP_prep_kernel<<<(npairs + 255) / 256, 256, 0, stream>>>(Ws, bs, W_out, b_out, ws);

    const int block = 256;
    const int threads_needed = (n + 1) / 2;
    const int grid = (threads_needed + block - 1) / block;
    MLP_89687507075104_kernel<<<grid, block, 0, stream>>>(
        x, reinterpret_cast<const f2*>(ws), out, n);
}